// Round 1
// baseline (127.561 us; speedup 1.0000x reference)
//
#include <hip/hip_runtime.h>
#include <math.h>

#define HALO 3
#define TILE_IN 32                 // input rows per tile
#define LROWS (TILE_IN + 2*HALO)   // 38 LDS rows
#define W 128
#define TILE_OUT 16                // output half-rows per tile

__device__ __forceinline__ int refl128(int i) {
    i = (i < 0) ? (-1 - i) : i;        // symmetric (half-sample) reflect
    return (i > 127) ? (255 - i) : i;
}

__device__ __forceinline__ float2 vdot7(const float2* A) {
    // symmetric 7-tap h1 over A[0..6]
    float2 r;
    r.x = fmaf(-0.0107143f, A[0].x + A[6].x,
          fmaf( 0.0535714f, A[1].x + A[5].x,
          fmaf( 0.2607143f, A[2].x + A[4].x, -0.6071429f * A[3].x)));
    r.y = fmaf(-0.0107143f, A[0].y + A[6].y,
          fmaf( 0.0535714f, A[1].y + A[5].y,
          fmaf( 0.2607143f, A[2].y + A[4].y, -0.6071429f * A[3].y)));
    return r;
}

__device__ __forceinline__ float2 vdot5(const float2* A) {
    // symmetric 5-tap h0 over A[0..4]
    float2 r;
    r.x = fmaf(-0.05f, A[0].x + A[4].x, fmaf(0.25f, A[1].x + A[3].x, 0.5f * A[2].x));
    r.y = fmaf(-0.05f, A[0].y + A[4].y, fmaf(0.25f, A[1].y + A[3].y, 0.5f * A[2].y));
    return r;
}

__device__ __forceinline__ float magf(float re, float im) {
    return sqrtf(fmaf(re, re, fmaf(im, im, 1.0e-4f))) - 0.01f;
}

__global__ __launch_bounds__(256) void scat_j1_kernel(
    const float* __restrict__ x,
    float* __restrict__ out_ll,
    float* __restrict__ out_r)
{
    __shared__ float slo[LROWS][W];
    __shared__ float shi[LROWS][W];

    const int bid   = blockIdx.x;
    const int plane = bid >> 2;        // n*64 + c   (0..2047)
    const int tile  = bid & 3;         // 0..3
    const int r0    = tile * TILE_IN;
    const int tid   = threadIdx.x;

    const float h0a = -0.05f,      h0b = 0.25f,      h0c = 0.5f;
    const float h1a = -0.0107143f, h1b = 0.0535714f, h1c = 0.2607143f, h1d = -0.6071429f;

    const float* __restrict__ xp = x + (size_t)plane * (W * W);

    // ---- Phase 1: horizontal 5/7-tap filters, write lo/hi strips to LDS ----
    #pragma unroll 1
    for (int it = 0; it < (LROWS * W) / 256; ++it) {   // 19 iterations
        int idx = tid + it * 256;
        int lr  = idx >> 7;            // 0..37
        int c   = idx & (W - 1);
        int q   = refl128(r0 - HALO + lr);
        const float* row = xp + q * W;
        float v[7];
        #pragma unroll
        for (int k = 0; k < 7; ++k)
            v[k] = row[refl128(c - 3 + k)];
        slo[lr][c] = fmaf(h0a, v[1] + v[5], fmaf(h0b, v[2] + v[4], h0c * v[3]));
        shi[lr][c] = fmaf(h1a, v[0] + v[6],
                     fmaf(h1b, v[1] + v[5],
                     fmaf(h1c, v[2] + v[4], h1d * v[3])));
    }
    __syncthreads();

    // ---- Phase 2: vertical filters + q2c + magnitudes + ll pool ----
    const int J   = tid & 63;          // output col 0..63
    const int Ib  = tid >> 6;          // 0..3
    const int c0  = 2 * J;
    const int n   = plane >> 6;
    const int ch  = plane & 63;
    const float S = 0.70710678118654752f;

    #pragma unroll 1
    for (int k = 0; k < 4; ++k) {
        const int Il = Ib + 4 * k;     // local output half-row 0..15
        const int R0 = 2 * Il;         // LDS row base (7-tap top starts here)

        float2 L[8], H[8];
        #pragma unroll
        for (int t = 0; t < 8; ++t) {
            L[t] = *(const float2*)&slo[R0 + t][c0];
            H[t] = *(const float2*)&shi[R0 + t][c0];
        }

        // vertical filters; top = full-res row 2*Il, bottom = 2*Il+1
        float2 lh_t = vdot7(L);        // rows R0..R0+6
        float2 lh_b = vdot7(L + 1);    // rows R0+1..R0+7
        float2 ll_t = vdot5(L + 1);    // rows R0+1..R0+5
        float2 ll_b = vdot5(L + 2);
        float2 hh_t = vdot7(H);
        float2 hh_b = vdot7(H + 1);
        float2 hl_t = vdot5(H + 1);
        float2 hl_b = vdot5(H + 2);

        // q2c: a=y[2I][2J] b=y[2I][2J+1] c=y[2I+1][2J] d=y[2I+1][2J+1], all * 1/sqrt(2)
        float a, b, c_, d;
        a = S * lh_t.x; b = S * lh_t.y; c_ = S * lh_b.x; d = S * lh_b.y;
        const float m15  = magf(a - d, b + c_);
        const float m165 = magf(a + d, b - c_);
        a = S * hh_t.x; b = S * hh_t.y; c_ = S * hh_b.x; d = S * hh_b.y;
        const float m45  = magf(a - d, b + c_);
        const float m135 = magf(a + d, b - c_);
        a = S * hl_t.x; b = S * hl_t.y; c_ = S * hl_b.x; d = S * hl_b.y;
        const float m75  = magf(a - d, b + c_);
        const float m105 = magf(a + d, b - c_);

        const int I = tile * TILE_OUT + Il;

        // ll: 2x2 average pool
        out_ll[(size_t)plane * 4096 + I * 64 + J] =
            0.25f * (ll_t.x + ll_t.y + ll_b.x + ll_b.y);

        // r: (n, 6*64, 64, 64), channel = orient*64 + ch
        const size_t rb = ((size_t)(n * 384 + ch)) * 4096 + (size_t)I * 64 + J;
        out_r[rb + 0u * 262144] = m15;
        out_r[rb + 1u * 262144] = m45;
        out_r[rb + 2u * 262144] = m75;
        out_r[rb + 3u * 262144] = m105;
        out_r[rb + 4u * 262144] = m135;
        out_r[rb + 5u * 262144] = m165;
    }
}

extern "C" void kernel_launch(void* const* d_in, const int* in_sizes, int n_in,
                              void* d_out, int out_size, void* d_ws, size_t ws_size,
                              hipStream_t stream) {
    const float* x = (const float*)d_in[0];
    float* out = (float*)d_out;
    float* out_ll = out;                 // 32*64*64*64 = 8388608 floats
    float* out_r  = out + 8388608;       // 32*384*64*64 = 50331648 floats

    dim3 grid(2048 * 4);                 // (n*c) planes * 4 row-tiles
    dim3 block(256);
    hipLaunchKernelGGL(scat_j1_kernel, grid, block, 0, stream, x, out_ll, out_r);
}

// Round 2
// 78.688 us; speedup vs baseline: 1.6211x; 1.6211x over previous
//
#include <hip/hip_runtime.h>
#include <math.h>

#define HALO 3
#define TILE_IN 32                 // input rows per tile
#define LROWS (TILE_IN + 2*HALO)   // 38 LDS rows
#define W 128
#define TILE_OUT 16                // output half-rows per tile

__device__ __forceinline__ int refl128(int i) {
    i = (i < 0) ? (-1 - i) : i;        // symmetric (half-sample) reflect
    return (i > 127) ? (255 - i) : i;
}

__device__ __forceinline__ float2 vdot7(const float2* A) {
    float2 r;
    r.x = fmaf(-0.0107143f, A[0].x + A[6].x,
          fmaf( 0.0535714f, A[1].x + A[5].x,
          fmaf( 0.2607143f, A[2].x + A[4].x, -0.6071429f * A[3].x)));
    r.y = fmaf(-0.0107143f, A[0].y + A[6].y,
          fmaf( 0.0535714f, A[1].y + A[5].y,
          fmaf( 0.2607143f, A[2].y + A[4].y, -0.6071429f * A[3].y)));
    return r;
}

__device__ __forceinline__ float2 vdot5(const float2* A) {
    float2 r;
    r.x = fmaf(-0.05f, A[0].x + A[4].x, fmaf(0.25f, A[1].x + A[3].x, 0.5f * A[2].x));
    r.y = fmaf(-0.05f, A[0].y + A[4].y, fmaf(0.25f, A[1].y + A[3].y, 0.5f * A[2].y));
    return r;
}

__device__ __forceinline__ float magf(float re, float im) {
    return sqrtf(fmaf(re, re, fmaf(im, im, 1.0e-4f))) - 0.01f;
}

__global__ __launch_bounds__(256) void scat_j1_kernel(
    const float* __restrict__ x,
    float* __restrict__ out_ll,
    float* __restrict__ out_r)
{
    __shared__ float slo[LROWS][W];
    __shared__ float shi[LROWS][W];

    const int bid   = blockIdx.x;
    const int plane = bid >> 2;        // n*64 + c   (0..2047)
    const int tile  = bid & 3;         // 0..3
    const int r0    = tile * TILE_IN;
    const int tid   = threadIdx.x;

    const float* __restrict__ xp = x + (size_t)plane * (W * W);

    // ---- Phase 1: horizontal 5/7-tap filters (vectorized), write lo/hi to LDS ----
    {
        const int g  = tid & 31;       // 4-col group 0..31
        const int rb = tid >> 5;       // 0..7 row within pass
        #pragma unroll
        for (int it = 0; it < 5; ++it) {
            const int lr = it * 8 + rb;           // 0..39
            if (lr < LROWS) {
                const int q = refl128(r0 - HALO + lr);
                const float4* __restrict__ rv = (const float4*)(xp + (size_t)q * W);
                const float4 B = rv[g];
                float4 A = rv[g > 0 ? g - 1 : 0];
                float4 C = rv[g < 31 ? g + 1 : 31];
                const float4 revB = make_float4(B.w, B.z, B.y, B.x);
                if (g == 0)  A = revB;            // cols -4..-1 reflected
                if (g == 31) C = revB;            // cols 128..131 reflected
                // window cols 4g-3 .. 4g+6
                const float wv[10] = {A.y, A.z, A.w, B.x, B.y, B.z, B.w, C.x, C.y, C.z};
                float4 lo4, hi4;
                float* lop = &lo4.x;
                float* hip_ = &hi4.x;
                #pragma unroll
                for (int j = 0; j < 4; ++j) {
                    const float sA = wv[j]     + wv[j + 6];
                    const float sB = wv[j + 1] + wv[j + 5];
                    const float sC = wv[j + 2] + wv[j + 4];
                    const float ct = wv[j + 3];
                    lop[j]  = fmaf(-0.05f, sB, fmaf(0.25f, sC, 0.5f * ct));
                    hip_[j] = fmaf(-0.0107143f, sA,
                              fmaf( 0.0535714f, sB,
                              fmaf( 0.2607143f, sC, -0.6071429f * ct)));
                }
                ((float4*)&slo[lr][0])[g] = lo4;
                ((float4*)&shi[lr][0])[g] = hi4;
            }
        }
    }
    __syncthreads();

    // ---- Phase 2: vertical filters + q2c + magnitudes + ll pool (rolling window) ----
    const int J     = tid & 63;        // output col 0..63
    const int Ib    = tid >> 6;        // 0..3 -> owns half-rows Ib*4 .. Ib*4+3
    const int c0    = 2 * J;
    const int n     = plane >> 6;
    const int ch    = plane & 63;
    const int Rbase = Ib * 8;
    const float S   = 0.70710678118654752f;

    float2 L[8], H[8];
    #pragma unroll
    for (int t = 0; t < 8; ++t) {
        L[t] = *(const float2*)&slo[Rbase + t][c0];
        H[t] = *(const float2*)&shi[Rbase + t][c0];
    }

    #pragma unroll
    for (int k = 0; k < 4; ++k) {
        // window = LDS rows Rbase+2k .. Rbase+2k+7, held in L[0..7]/H[0..7]
        const float2 lh_t = vdot7(L);
        const float2 lh_b = vdot7(L + 1);
        const float2 ll_t = vdot5(L + 1);
        const float2 ll_b = vdot5(L + 2);
        const float2 hh_t = vdot7(H);
        const float2 hh_b = vdot7(H + 1);
        const float2 hl_t = vdot5(H + 1);
        const float2 hl_b = vdot5(H + 2);

        float a, b, c_, d;
        a = S * lh_t.x; b = S * lh_t.y; c_ = S * lh_b.x; d = S * lh_b.y;
        const float m15  = magf(a - d, b + c_);
        const float m165 = magf(a + d, b - c_);
        a = S * hh_t.x; b = S * hh_t.y; c_ = S * hh_b.x; d = S * hh_b.y;
        const float m45  = magf(a - d, b + c_);
        const float m135 = magf(a + d, b - c_);
        a = S * hl_t.x; b = S * hl_t.y; c_ = S * hl_b.x; d = S * hl_b.y;
        const float m75  = magf(a - d, b + c_);
        const float m105 = magf(a + d, b - c_);

        const int Il = Ib * 4 + k;
        const int I  = tile * TILE_OUT + Il;

        __builtin_nontemporal_store(
            0.25f * (ll_t.x + ll_t.y + ll_b.x + ll_b.y),
            &out_ll[(size_t)plane * 4096 + I * 64 + J]);

        float* rb_p = out_r + ((size_t)(n * 384 + ch)) * 4096 + (size_t)I * 64 + J;
        __builtin_nontemporal_store(m15,  rb_p + 0u * 262144);
        __builtin_nontemporal_store(m45,  rb_p + 1u * 262144);
        __builtin_nontemporal_store(m75,  rb_p + 2u * 262144);
        __builtin_nontemporal_store(m105, rb_p + 3u * 262144);
        __builtin_nontemporal_store(m135, rb_p + 4u * 262144);
        __builtin_nontemporal_store(m165, rb_p + 5u * 262144);

        if (k < 3) {
            #pragma unroll
            for (int t = 0; t < 6; ++t) { L[t] = L[t + 2]; H[t] = H[t + 2]; }
            const int rn = Rbase + 8 + 2 * k;
            L[6] = *(const float2*)&slo[rn][c0];
            L[7] = *(const float2*)&slo[rn + 1][c0];
            H[6] = *(const float2*)&shi[rn][c0];
            H[7] = *(const float2*)&shi[rn + 1][c0];
        }
    }
}

extern "C" void kernel_launch(void* const* d_in, const int* in_sizes, int n_in,
                              void* d_out, int out_size, void* d_ws, size_t ws_size,
                              hipStream_t stream) {
    const float* x = (const float*)d_in[0];
    float* out = (float*)d_out;
    float* out_ll = out;                 // 32*64*64*64 = 8388608 floats
    float* out_r  = out + 8388608;       // 32*384*64*64 = 50331648 floats

    dim3 grid(2048 * 4);                 // (n*c) planes * 4 row-tiles
    dim3 block(256);
    hipLaunchKernelGGL(scat_j1_kernel, grid, block, 0, stream, x, out_ll, out_r);
}

// Round 3
// 77.135 us; speedup vs baseline: 1.6537x; 1.0201x over previous
//
#include <hip/hip_runtime.h>
#include <math.h>

#define HALO 3
#define TILE_IN 16                 // input rows per tile
#define LROWS (TILE_IN + 2*HALO)   // 22 LDS rows
#define W 128
#define TILE_OUT 8                 // output half-rows per tile
#define NTILES 8

__device__ __forceinline__ int refl128(int i) {
    i = (i < 0) ? (-1 - i) : i;        // symmetric (half-sample) reflect
    return (i > 127) ? (255 - i) : i;
}

__device__ __forceinline__ float2 vdot7(const float2* A) {
    float2 r;
    r.x = fmaf(-0.0107143f, A[0].x + A[6].x,
          fmaf( 0.0535714f, A[1].x + A[5].x,
          fmaf( 0.2607143f, A[2].x + A[4].x, -0.6071429f * A[3].x)));
    r.y = fmaf(-0.0107143f, A[0].y + A[6].y,
          fmaf( 0.0535714f, A[1].y + A[5].y,
          fmaf( 0.2607143f, A[2].y + A[4].y, -0.6071429f * A[3].y)));
    return r;
}

__device__ __forceinline__ float2 vdot5(const float2* A) {
    float2 r;
    r.x = fmaf(-0.05f, A[0].x + A[4].x, fmaf(0.25f, A[1].x + A[3].x, 0.5f * A[2].x));
    r.y = fmaf(-0.05f, A[0].y + A[4].y, fmaf(0.25f, A[1].y + A[3].y, 0.5f * A[2].y));
    return r;
}

__device__ __forceinline__ float magf(float re, float im) {
    return sqrtf(fmaf(re, re, fmaf(im, im, 1.0e-4f))) - 0.01f;
}

__global__ __launch_bounds__(256) void scat_j1_kernel(
    const float* __restrict__ x,
    float* __restrict__ out_ll,
    float* __restrict__ out_r)
{
    __shared__ float slo[LROWS][W];
    __shared__ float shi[LROWS][W];

    // XCD-chunked swizzle: consecutive logical ids (same plane's tiles)
    // land on the same XCD back-to-back -> halo rows hit in L2.
    // grid = 16384 = 8 * 2048, bijective.
    const int raw   = blockIdx.x;
    const int L_id  = (raw & 7) * 2048 + (raw >> 3);
    const int plane = L_id >> 3;       // n*64 + c   (0..2047)
    const int tile  = L_id & 7;        // 0..7
    const int r0    = tile * TILE_IN;
    const int tid   = threadIdx.x;

    const float* __restrict__ xp = x + (size_t)plane * (W * W);

    // ---- Phase 1: horizontal 5/7-tap filters (vectorized), write lo/hi to LDS ----
    {
        const int g  = tid & 31;       // 4-col group 0..31
        const int rb = tid >> 5;       // 0..7 row within pass
        #pragma unroll
        for (int it = 0; it < 3; ++it) {
            const int lr = it * 8 + rb;           // 0..23
            if (lr < LROWS) {
                const int q = refl128(r0 - HALO + lr);
                const float4* __restrict__ rv = (const float4*)(xp + (size_t)q * W);
                const float4 B = rv[g];
                float4 A = rv[g > 0 ? g - 1 : 0];
                float4 C = rv[g < 31 ? g + 1 : 31];
                const float4 revB = make_float4(B.w, B.z, B.y, B.x);
                if (g == 0)  A = revB;            // cols -4..-1 reflected
                if (g == 31) C = revB;            // cols 128..131 reflected
                // window cols 4g-3 .. 4g+6
                const float wv[10] = {A.y, A.z, A.w, B.x, B.y, B.z, B.w, C.x, C.y, C.z};
                float4 lo4, hi4;
                float* lop = &lo4.x;
                float* hip_ = &hi4.x;
                #pragma unroll
                for (int j = 0; j < 4; ++j) {
                    const float sA = wv[j]     + wv[j + 6];
                    const float sB = wv[j + 1] + wv[j + 5];
                    const float sC = wv[j + 2] + wv[j + 4];
                    const float ct = wv[j + 3];
                    lop[j]  = fmaf(-0.05f, sB, fmaf(0.25f, sC, 0.5f * ct));
                    hip_[j] = fmaf(-0.0107143f, sA,
                              fmaf( 0.0535714f, sB,
                              fmaf( 0.2607143f, sC, -0.6071429f * ct)));
                }
                ((float4*)&slo[lr][0])[g] = lo4;
                ((float4*)&shi[lr][0])[g] = hi4;
            }
        }
    }
    __syncthreads();

    // ---- Phase 2: vertical filters + q2c + magnitudes + ll pool (rolling window) ----
    const int J     = tid & 63;        // output col 0..63
    const int Ib    = tid >> 6;        // 0..3 -> owns half-rows Ib*2, Ib*2+1
    const int c0    = 2 * J;
    const int n     = plane >> 6;
    const int ch    = plane & 63;
    const int Rbase = Ib * 4;
    const float S   = 0.70710678118654752f;

    float2 L[8], H[8];
    #pragma unroll
    for (int t = 0; t < 8; ++t) {
        L[t] = *(const float2*)&slo[Rbase + t][c0];
        H[t] = *(const float2*)&shi[Rbase + t][c0];
    }

    #pragma unroll
    for (int k = 0; k < 2; ++k) {
        // window = LDS rows Rbase+2k .. Rbase+2k+7, held in L[0..7]/H[0..7]
        const float2 lh_t = vdot7(L);
        const float2 lh_b = vdot7(L + 1);
        const float2 ll_t = vdot5(L + 1);
        const float2 ll_b = vdot5(L + 2);
        const float2 hh_t = vdot7(H);
        const float2 hh_b = vdot7(H + 1);
        const float2 hl_t = vdot5(H + 1);
        const float2 hl_b = vdot5(H + 2);

        float a, b, c_, d;
        a = S * lh_t.x; b = S * lh_t.y; c_ = S * lh_b.x; d = S * lh_b.y;
        const float m15  = magf(a - d, b + c_);
        const float m165 = magf(a + d, b - c_);
        a = S * hh_t.x; b = S * hh_t.y; c_ = S * hh_b.x; d = S * hh_b.y;
        const float m45  = magf(a - d, b + c_);
        const float m135 = magf(a + d, b - c_);
        a = S * hl_t.x; b = S * hl_t.y; c_ = S * hl_b.x; d = S * hl_b.y;
        const float m75  = magf(a - d, b + c_);
        const float m105 = magf(a + d, b - c_);

        const int Il = Ib * 2 + k;
        const int I  = tile * TILE_OUT + Il;

        __builtin_nontemporal_store(
            0.25f * (ll_t.x + ll_t.y + ll_b.x + ll_b.y),
            &out_ll[(size_t)plane * 4096 + I * 64 + J]);

        float* rb_p = out_r + ((size_t)(n * 384 + ch)) * 4096 + (size_t)I * 64 + J;
        __builtin_nontemporal_store(m15,  rb_p + 0u * 262144);
        __builtin_nontemporal_store(m45,  rb_p + 1u * 262144);
        __builtin_nontemporal_store(m75,  rb_p + 2u * 262144);
        __builtin_nontemporal_store(m105, rb_p + 3u * 262144);
        __builtin_nontemporal_store(m135, rb_p + 4u * 262144);
        __builtin_nontemporal_store(m165, rb_p + 5u * 262144);

        if (k == 0) {
            #pragma unroll
            for (int t = 0; t < 6; ++t) { L[t] = L[t + 2]; H[t] = H[t + 2]; }
            const int rn = Rbase + 8;
            L[6] = *(const float2*)&slo[rn][c0];
            L[7] = *(const float2*)&slo[rn + 1][c0];
            H[6] = *(const float2*)&shi[rn][c0];
            H[7] = *(const float2*)&shi[rn + 1][c0];
        }
    }
}

extern "C" void kernel_launch(void* const* d_in, const int* in_sizes, int n_in,
                              void* d_out, int out_size, void* d_ws, size_t ws_size,
                              hipStream_t stream) {
    const float* x = (const float*)d_in[0];
    float* out = (float*)d_out;
    float* out_ll = out;                 // 32*64*64*64 = 8388608 floats
    float* out_r  = out + 8388608;       // 32*384*64*64 = 50331648 floats

    dim3 grid(2048 * NTILES);            // (n*c) planes * 8 row-tiles
    dim3 block(256);
    hipLaunchKernelGGL(scat_j1_kernel, grid, block, 0, stream, x, out_ll, out_r);
}